// Round 14
// baseline (947.975 us; speedup 1.0000x reference)
//
#include <hip/hip_runtime.h>
#include <hip/hip_fp16.h>
#include <math.h>

#define HID 128
#define EPS 1e-5f
#define BK 64          // dst nodes per bucket
#define MAXNBK 2048    // supports n <= 131072
#define NSTRIPE 16     // BN-stats atomic striping
#define PADK 136       // fp16 LDS row stride: 68 words % 32 = 4 -> conflict-free MFMA frag reads

typedef _Float16 half8 __attribute__((ext_vector_type(8)));
typedef float f32x4 __attribute__((ext_vector_type(4)));

// ---------------- bucketed graph preprocessing ----------------
// btmp entry: (src << 6) | (dst & 63)

__global__ __launch_bounds__(256) void k_bhist(const int* __restrict__ dst, int* __restrict__ bcount,
                                               int e, int nbk) {
    __shared__ int hist[MAXNBK];
    for (int i = threadIdx.x; i < nbk; i += 256) hist[i] = 0;
    __syncthreads();
    int base = blockIdx.x * 4096;
    int end = min(base + 4096, e);
    for (int i = base + threadIdx.x; i < end; i += 256) atomicAdd(&hist[dst[i] >> 6], 1);
    __syncthreads();
    for (int i = threadIdx.x; i < nbk; i += 256) {
        int c = hist[i];
        if (c) atomicAdd(&bcount[i * 16], c);
    }
}

__global__ __launch_bounds__(1024) void k_bscan(const int* __restrict__ bcount, int* __restrict__ boffs,
                                                int* __restrict__ bcur, int nbk, int e) {
    __shared__ int lds[1024];
    int tid = threadIdx.x;
    int i0 = 2 * tid, i1 = 2 * tid + 1;
    int a = (i0 < nbk) ? bcount[i0 * 16] : 0;
    int b = (i1 < nbk) ? bcount[i1 * 16] : 0;
    lds[tid] = a + b;
    __syncthreads();
    for (int off = 1; off < 1024; off <<= 1) {
        int v = (tid >= off) ? lds[tid - off] : 0;
        __syncthreads();
        lds[tid] += v;
        __syncthreads();
    }
    int excl = lds[tid] - (a + b);
    if (i0 < nbk) { boffs[i0] = excl;     bcur[i0 * 16] = excl; }
    if (i1 < nbk) { boffs[i1] = excl + a; bcur[i1 * 16] = excl + a; }
    if (tid == 1023) boffs[nbk] = e;
}

__global__ __launch_bounds__(1024) void k_bscatter(const int* __restrict__ src, const int* __restrict__ dst,
                                                   int* __restrict__ bcur, int* __restrict__ btmp,
                                                   int e, int nbk) {
    __shared__ int hist[MAXNBK];
    int tid = threadIdx.x;
    for (int i = tid; i < nbk; i += 1024) hist[i] = 0;
    __syncthreads();
    int per = (e + gridDim.x - 1) / gridDim.x;
    int base = blockIdx.x * per;
    int end = min(base + per, e);
    for (int i = base + tid; i < end; i += 1024) atomicAdd(&hist[dst[i] >> 6], 1);
    __syncthreads();
    for (int i = tid; i < nbk; i += 1024) {
        int c = hist[i];
        hist[i] = c ? atomicAdd(&bcur[i * 16], c) : 0;
    }
    __syncthreads();
    for (int i = base + tid; i < end; i += 1024) {
        int d = dst[i];
        int pos = atomicAdd(&hist[d >> 6], 1);          // LDS int atomic (native)
        btmp[pos] = (src[i] << 6) | (d & 63);
    }
}

__global__ __launch_bounds__(256) void k_bsort(const int* __restrict__ btmp, const int* __restrict__ boffs,
                                               int* __restrict__ csr, int* __restrict__ offs,
                                               float* __restrict__ dinv, int n, int etot) {
    __shared__ int cnt[BK];
    __shared__ int cur[BK];
    int b = blockIdx.x, tid = threadIdx.x;
    if (tid < BK) cnt[tid] = 0;
    __syncthreads();
    int e0 = boffs[b], e1 = boffs[b + 1];
    for (int i = e0 + tid; i < e1; i += 256) atomicAdd(&cnt[btmp[i] & 63], 1);
    __syncthreads();
    if (tid == 0) {
        int run = 0;
        for (int d = 0; d < BK; ++d) { cur[d] = run; run += cnt[d]; }
    }
    __syncthreads();
    if (tid < BK) {
        int node = b * BK + tid;
        if (node < n) {
            offs[node] = e0 + cur[tid];
            dinv[node] = rsqrtf((float)(cnt[tid] + 1));  // +1 self-loop
        }
    }
    if (b == 0 && tid == 0) offs[n] = etot;
    __syncthreads();
    for (int i = e0 + tid; i < e1; i += 256) {
        int p = btmp[i];
        int pos = e0 + atomicAdd(&cur[p & 63], 1);
        csr[pos] = p >> 6;
    }
}

// ---------------- weight transpose to fp16 ----------------

__global__ void k_prepw(const float* __restrict__ W, _Float16* __restrict__ Wt) {
    int idx = blockIdx.x * 256 + threadIdx.x;   // 128*128
    int k = idx >> 7, nn = idx & 127;
    Wt[nn * 128 + k] = (_Float16)W[k * 128 + nn];
}

__global__ void k_prepwf(const float* __restrict__ W, _Float16* __restrict__ Wt) {
    int idx = blockIdx.x * 256 + threadIdx.x;   // 128*32
    int k = idx >> 5, nn = idx & 31;
    Wt[nn * 128 + k] = (_Float16)W[k * 32 + nn];
}

// ---------------- MFMA GEMM layer 1 with fused embed -----------------------------------

__global__ __launch_bounds__(256) void k_mm1(const float* __restrict__ x, const float* __restrict__ We,
                                             const float* __restrict__ be, const _Float16* __restrict__ Wt,
                                             const float* __restrict__ dinv, __half2* __restrict__ th,
                                             __half2* __restrict__ h, int n) {
    __shared__ __attribute__((aligned(16))) _Float16 Ah[64][PADK];
    __shared__ __attribute__((aligned(16))) _Float16 Bh[128][PADK];
    __shared__ float W0s[128], W1s[128], bes[128];
    int tid = threadIdx.x;
    int nb = blockIdx.x * 64;
    if (tid < 128) { W0s[tid] = We[tid]; W1s[tid] = We[128 + tid]; bes[tid] = be[tid]; }
    __syncthreads();
    uint2* h2p = (uint2*)h;
    const float2* x2 = (const float2*)x;
#pragma unroll
    for (int r = 0; r < 8; ++r) {
        int idx = r * 256 + tid;
        int ni = idx >> 5, k4 = idx & 31;
        int node = nb + ni;
        float4 v = make_float4(0.f, 0.f, 0.f, 0.f);
        union { __half2 h2[2]; uint2 u; } pk;
        if (node < n) {
            float2 xx = x2[node];
            float4 w0 = *((const float4*)&W0s[k4 * 4]);
            float4 w1 = *((const float4*)&W1s[k4 * 4]);
            float4 bb = *((const float4*)&bes[k4 * 4]);
            v.x = fmaxf(xx.x * w0.x + xx.y * w1.x + bb.x, 0.f);
            v.y = fmaxf(xx.x * w0.y + xx.y * w1.y + bb.y, 0.f);
            v.z = fmaxf(xx.x * w0.z + xx.y * w1.z + bb.z, 0.f);
            v.w = fmaxf(xx.x * w0.w + xx.y * w1.w + bb.w, 0.f);
            pk.h2[0] = __floats2half2_rn(v.x, v.y);
            pk.h2[1] = __floats2half2_rn(v.z, v.w);
            h2p[(size_t)node * 32 + k4] = pk.u;   // h stored fp16 for layer-2 residual
        } else {
            pk.h2[0] = __floats2half2_rn(0.f, 0.f);
            pk.h2[1] = __floats2half2_rn(0.f, 0.f);
        }
        *(uint2*)&Ah[ni][k4 * 4] = pk.u;
    }
    const uint4* wt4 = (const uint4*)Wt;
#pragma unroll
    for (int r = 0; r < 8; ++r) {
        int idx = r * 256 + tid;
        int row = idx >> 4, ch = idx & 15;
        *(uint4*)&Bh[row][ch * 8] = wt4[row * 16 + ch];
    }
    __syncthreads();
    int lane = tid & 63, w = tid >> 6;
    int mrow = lane & 15, quad = lane >> 4;
    f32x4 acc[8];
#pragma unroll
    for (int t = 0; t < 8; ++t) acc[t] = (f32x4){0.f, 0.f, 0.f, 0.f};
#pragma unroll
    for (int kc = 0; kc < 4; ++kc) {
        half8 av = *(half8*)&Ah[w * 16 + mrow][kc * 32 + quad * 8];
#pragma unroll
        for (int t = 0; t < 8; ++t) {
            half8 bv = *(half8*)&Bh[t * 16 + mrow][kc * 32 + quad * 8];
            acc[t] = __builtin_amdgcn_mfma_f32_16x16x32_f16(av, bv, acc[t], 0, 0, 0);
        }
    }
    float dv[4];
#pragma unroll
    for (int r = 0; r < 4; ++r) {
        int node = nb + w * 16 + quad * 4 + r;
        dv[r] = (node < n) ? dinv[node] : 0.f;
    }
    __syncthreads();   // Ah reads done; reuse as output repack tile
#pragma unroll
    for (int t = 0; t < 8; ++t)
#pragma unroll
        for (int r = 0; r < 4; ++r)
            Ah[w * 16 + quad * 4 + r][t * 16 + mrow] = (_Float16)(acc[t][r] * dv[r]);
    __syncthreads();
#pragma unroll
    for (int it = 0; it < 4; ++it) {
        int idx = it * 256 + tid;
        int row = idx >> 4, ch = idx & 15;
        int node = nb + row;
        if (node < n)
            ((uint4*)th)[(size_t)node * 16 + ch] = *(uint4*)&Ah[row][ch * 8];
    }
}

// ---------------- MFMA GEMM fused with BN-finalize+apply+ReLU+residual (layers 2,3) ----

__global__ __launch_bounds__(256) void k_mmf(const __half2* __restrict__ agg, __half2* __restrict__ h,
                                             const float* __restrict__ S, const float* __restrict__ SS,
                                             const float* __restrict__ g, const float* __restrict__ bt,
                                             const _Float16* __restrict__ Wt, const float* __restrict__ dinv,
                                             __half2* __restrict__ th, int n) {
    __shared__ __attribute__((aligned(16))) _Float16 Ah[64][PADK];
    __shared__ __attribute__((aligned(16))) _Float16 Bh[128][PADK];
    __shared__ float As[128], Cs[128];
    int tid = threadIdx.x;
    int nb = blockIdx.x * 64;
    if (tid < 128) {
        float s = 0.f, q = 0.f;
#pragma unroll
        for (int k = 0; k < NSTRIPE; ++k) { s += S[k * 128 + tid]; q += SS[k * 128 + tid]; }
        float mu = s / (float)n;
        float var = q / (float)n - mu * mu;
        float inv = rsqrtf(var + EPS);
        As[tid] = g[tid] * inv;
        Cs[tid] = bt[tid] - mu * g[tid] * inv;
    }
    __syncthreads();
    const uint2* a2p = (const uint2*)agg;
    uint2* h2p = (uint2*)h;
#pragma unroll
    for (int r = 0; r < 8; ++r) {
        int idx = r * 256 + tid;
        int ni = idx >> 5, k4 = idx & 31;
        int node = nb + ni;
        union { __half2 h2[2]; uint2 u; } pk;
        if (node < n) {
            uint2 au = a2p[(size_t)node * 32 + k4];
            uint2 hu = h2p[(size_t)node * 32 + k4];
            float2 a01 = __half22float2(*(__half2*)&au.x);
            float2 a23 = __half22float2(*(__half2*)&au.y);
            float2 h01 = __half22float2(*(__half2*)&hu.x);
            float2 h23 = __half22float2(*(__half2*)&hu.y);
            float4 aa = *((const float4*)&As[k4 * 4]);
            float4 cc = *((const float4*)&Cs[k4 * 4]);
            float v0 = fmaxf(a01.x * aa.x + cc.x, 0.f) + h01.x;
            float v1 = fmaxf(a01.y * aa.y + cc.y, 0.f) + h01.y;
            float v2 = fmaxf(a23.x * aa.z + cc.z, 0.f) + h23.x;
            float v3 = fmaxf(a23.y * aa.w + cc.w, 0.f) + h23.y;
            pk.h2[0] = __floats2half2_rn(v0, v1);
            pk.h2[1] = __floats2half2_rn(v2, v3);
            h2p[(size_t)node * 32 + k4] = pk.u;   // in-place: element owned by one thread
        } else {
            pk.h2[0] = __floats2half2_rn(0.f, 0.f);
            pk.h2[1] = __floats2half2_rn(0.f, 0.f);
        }
        *(uint2*)&Ah[ni][k4 * 4] = pk.u;
    }
    const uint4* wt4 = (const uint4*)Wt;
#pragma unroll
    for (int r = 0; r < 8; ++r) {
        int idx = r * 256 + tid;
        int row = idx >> 4, ch = idx & 15;
        *(uint4*)&Bh[row][ch * 8] = wt4[row * 16 + ch];
    }
    __syncthreads();
    int lane = tid & 63, w = tid >> 6;
    int mrow = lane & 15, quad = lane >> 4;
    f32x4 acc[8];
#pragma unroll
    for (int t = 0; t < 8; ++t) acc[t] = (f32x4){0.f, 0.f, 0.f, 0.f};
#pragma unroll
    for (int kc = 0; kc < 4; ++kc) {
        half8 av = *(half8*)&Ah[w * 16 + mrow][kc * 32 + quad * 8];
#pragma unroll
        for (int t = 0; t < 8; ++t) {
            half8 bv = *(half8*)&Bh[t * 16 + mrow][kc * 32 + quad * 8];
            acc[t] = __builtin_amdgcn_mfma_f32_16x16x32_f16(av, bv, acc[t], 0, 0, 0);
        }
    }
    float dv[4];
#pragma unroll
    for (int r = 0; r < 4; ++r) {
        int node = nb + w * 16 + quad * 4 + r;
        dv[r] = (node < n) ? dinv[node] : 0.f;
    }
    __syncthreads();
#pragma unroll
    for (int t = 0; t < 8; ++t)
#pragma unroll
        for (int r = 0; r < 4; ++r)
            Ah[w * 16 + quad * 4 + r][t * 16 + mrow] = (_Float16)(acc[t][r] * dv[r]);
    __syncthreads();
#pragma unroll
    for (int it = 0; it < 4; ++it) {
        int idx = it * 256 + tid;
        int row = idx >> 4, ch = idx & 15;
        int node = nb + row;
        if (node < n)
            ((uint4*)th)[(size_t)node * 16 + ch] = *(uint4*)&Ah[row][ch * 8];
    }
}

// ---------------- MFMA head GEMM: BN-finalize+apply+ReLU+residual -> @Wf1+bf1 + stats --

__global__ __launch_bounds__(256) void k_mmh(const __half2* __restrict__ agg, const __half2* __restrict__ h,
                                             const float* __restrict__ Sin, const float* __restrict__ SSin,
                                             const float* __restrict__ g, const float* __restrict__ bt,
                                             const _Float16* __restrict__ Wt, const float* __restrict__ bias,
                                             float* __restrict__ tf,
                                             float* __restrict__ S, float* __restrict__ SS, int n) {
    __shared__ __attribute__((aligned(16))) _Float16 Ah[64][PADK];
    __shared__ __attribute__((aligned(16))) _Float16 Bh[32][PADK];
    __shared__ float Ds[64][36];
    __shared__ float As[128], Cs[128];
    __shared__ float sredS[4][8][4], sredQ[4][8][4];
    int tid = threadIdx.x;
    int nb = blockIdx.x * 64;
    if (tid < 128) {
        float s = 0.f, q = 0.f;
#pragma unroll
        for (int k = 0; k < NSTRIPE; ++k) { s += Sin[k * 128 + tid]; q += SSin[k * 128 + tid]; }
        float mu = s / (float)n;
        float var = q / (float)n - mu * mu;
        float inv = rsqrtf(var + EPS);
        As[tid] = g[tid] * inv;
        Cs[tid] = bt[tid] - mu * g[tid] * inv;
    }
    __syncthreads();
    const uint2* a2p = (const uint2*)agg;
    const uint2* h2p = (const uint2*)h;
#pragma unroll
    for (int r = 0; r < 8; ++r) {
        int idx = r * 256 + tid;
        int ni = idx >> 5, k4 = idx & 31;
        int node = nb + ni;
        union { __half2 h2[2]; uint2 u; } pk;
        if (node < n) {
            uint2 au = a2p[(size_t)node * 32 + k4];
            uint2 hu = h2p[(size_t)node * 32 + k4];
            float2 a01 = __half22float2(*(__half2*)&au.x);
            float2 a23 = __half22float2(*(__half2*)&au.y);
            float2 h01 = __half22float2(*(__half2*)&hu.x);
            float2 h23 = __half22float2(*(__half2*)&hu.y);
            float4 aa = *((const float4*)&As[k4 * 4]);
            float4 cc = *((const float4*)&Cs[k4 * 4]);
            float v0 = fmaxf(a01.x * aa.x + cc.x, 0.f) + h01.x;
            float v1 = fmaxf(a01.y * aa.y + cc.y, 0.f) + h01.y;
            float v2 = fmaxf(a23.x * aa.z + cc.z, 0.f) + h23.x;
            float v3 = fmaxf(a23.y * aa.w + cc.w, 0.f) + h23.y;
            pk.h2[0] = __floats2half2_rn(v0, v1);
            pk.h2[1] = __floats2half2_rn(v2, v3);
        } else {
            pk.h2[0] = __floats2half2_rn(0.f, 0.f);
            pk.h2[1] = __floats2half2_rn(0.f, 0.f);
        }
        *(uint2*)&Ah[ni][k4 * 4] = pk.u;
    }
    const uint4* wt4 = (const uint4*)Wt;
#pragma unroll
    for (int r = 0; r < 2; ++r) {
        int idx = r * 256 + tid;
        int row = idx >> 4, ch = idx & 15;
        *(uint4*)&Bh[row][ch * 8] = wt4[row * 16 + ch];
    }
    __syncthreads();
    int lane = tid & 63, w = tid >> 6;
    int mrow = lane & 15, quad = lane >> 4;
    f32x4 acc[2];
    acc[0] = (f32x4){0.f, 0.f, 0.f, 0.f};
    acc[1] = (f32x4){0.f, 0.f, 0.f, 0.f};
#pragma unroll
    for (int kc = 0; kc < 4; ++kc) {
        half8 av = *(half8*)&Ah[w * 16 + mrow][kc * 32 + quad * 8];
#pragma unroll
        for (int t = 0; t < 2; ++t) {
            half8 bv = *(half8*)&Bh[t * 16 + mrow][kc * 32 + quad * 8];
            acc[t] = __builtin_amdgcn_mfma_f32_16x16x32_f16(av, bv, acc[t], 0, 0, 0);
        }
    }
#pragma unroll
    for (int t = 0; t < 2; ++t)
#pragma unroll
        for (int r = 0; r < 4; ++r)
            Ds[w * 16 + quad * 4 + r][t * 16 + mrow] = acc[t][r];
    __syncthreads();
    float ps0 = 0.f, ps1 = 0.f, ps2 = 0.f, ps3 = 0.f;
    float pq0 = 0.f, pq1 = 0.f, pq2 = 0.f, pq3 = 0.f;
    int c4 = tid & 7;
    float4 bb = ((const float4*)bias)[c4];
#pragma unroll
    for (int it = 0; it < 2; ++it) {
        int idx = it * 256 + tid;
        int row = idx >> 3;
        int node = nb + row;
        if (node < n) {
            float v0 = Ds[row][c4 * 4 + 0] + bb.x;
            float v1 = Ds[row][c4 * 4 + 1] + bb.y;
            float v2 = Ds[row][c4 * 4 + 2] + bb.z;
            float v3 = Ds[row][c4 * 4 + 3] + bb.w;
            *((float4*)&tf[(size_t)node * 32 + c4 * 4]) = make_float4(v0, v1, v2, v3);
            ps0 += v0; ps1 += v1; ps2 += v2; ps3 += v3;
            pq0 += v0 * v0; pq1 += v1 * v1; pq2 += v2 * v2; pq3 += v3 * v3;
        }
    }
#pragma unroll
    for (int off = 8; off < 64; off <<= 1) {
        ps0 += __shfl_down(ps0, off); ps1 += __shfl_down(ps1, off);
        ps2 += __shfl_down(ps2, off); ps3 += __shfl_down(ps3, off);
        pq0 += __shfl_down(pq0, off); pq1 += __shfl_down(pq1, off);
        pq2 += __shfl_down(pq2, off); pq3 += __shfl_down(pq3, off);
    }
    if (lane < 8) {
        sredS[w][lane][0] = ps0; sredS[w][lane][1] = ps1; sredS[w][lane][2] = ps2; sredS[w][lane][3] = ps3;
        sredQ[w][lane][0] = pq0; sredQ[w][lane][1] = pq1; sredQ[w][lane][2] = pq2; sredQ[w][lane][3] = pq3;
    }
    __syncthreads();
    if (tid < 32) {
        int cc4 = tid >> 2, j = tid & 3;
        float s = sredS[0][cc4][j] + sredS[1][cc4][j] + sredS[2][cc4][j] + sredS[3][cc4][j];
        float q = sredQ[0][cc4][j] + sredQ[1][cc4][j] + sredQ[2][cc4][j] + sredQ[3][cc4][j];
        int stripe = (blockIdx.x & (NSTRIPE - 1)) * 128;
        atomicAdd(&S[stripe + tid], s);
        atomicAdd(&SS[stripe + tid], q);
    }
}

// ---------------- aggregation + fused BN stats: XCD-affine feature slicing -------------
// Group g = blockIdx & 7 handles features [g*16, g*16+16) only. With round-robin
// block->XCD mapping, group g's working set (3.2 MB th slice) fits its XCD's 4 MB L2.
// Wave = 1 node; lane = es*4+fl: es = edge slot (16 edges per load instr), fl = 8B chunk.

__global__ __launch_bounds__(256) void k_agg(const __half2* __restrict__ t, const int* __restrict__ offs,
                                             const int* __restrict__ csr, const float* __restrict__ dinv,
                                             const float* __restrict__ bias, __half2* __restrict__ out,
                                             float* __restrict__ S, float* __restrict__ SS, int n) {
    __shared__ float ls[4][16];
    __shared__ float lss[4][16];
    int tid = threadIdx.x;
    int lane = tid & 63, w = tid >> 6;
    int g = blockIdx.x & 7;           // feature group -> XCD affinity
    int gb = blockIdx.x >> 3;         // 0..511 within group
    int es = lane >> 2, fl = lane & 3;
    int cbase = g * 4 + fl;           // uint2 chunk index within 32-chunk row
    const uint2* t4 = (const uint2*)t;
    float4 bb = ((const float4*)bias)[cbase];
    float s0 = 0.f, s1 = 0.f, s2 = 0.f, s3 = 0.f;
    float q0 = 0.f, q1 = 0.f, q2 = 0.f, q3 = 0.f;
    float selfm = (es == 0) ? 1.f : 0.f;
    int ngrp = (n + 3) >> 2;
    for (int grp = gb; grp < ngrp; grp += 512) {
        int node = grp * 4 + w;       // wave-uniform
        if (node < n) {
            uint2 rv = t4[(size_t)node * 32 + cbase];
            float2 f0 = __half22float2(*(__half2*)&rv.x);
            float2 f1 = __half22float2(*(__half2*)&rv.y);
            float a0 = f0.x * selfm, a1 = f0.y * selfm, a2 = f1.x * selfm, a3 = f1.y * selfm;
            int e0 = offs[node], e1 = offs[node + 1];
            for (int e = e0; e < e1; e += 16) {
                int i = e + es;
                int c = csr[min(i, e1 - 1)];
                uint2 r = t4[(size_t)c * 32 + cbase];
                float m = (i < e1) ? 1.f : 0.f;
                float2 g0 = __half22float2(*(__half2*)&r.x);
                float2 g1 = __half22float2(*(__half2*)&r.y);
                a0 += m * g0.x; a1 += m * g0.y; a2 += m * g1.x; a3 += m * g1.y;
            }
            // fold 16 edge slots (stride-4 lanes) down to es==0
#pragma unroll
            for (int off = 4; off < 64; off <<= 1) {
                a0 += __shfl_down(a0, off);
                a1 += __shfl_down(a1, off);
                a2 += __shfl_down(a2, off);
                a3 += __shfl_down(a3, off);
            }
            if (es == 0) {
                float di = dinv[node];
                float v0 = a0 * di + bb.x, v1 = a1 * di + bb.y;
                float v2 = a2 * di + bb.z, v3 = a3 * di + bb.w;
                union { __half2 h2[2]; uint2 u; } pk;
                pk.h2[0] = __floats2half2_rn(v0, v1);
                pk.h2[1] = __floats2half2_rn(v2, v3);
                ((uint2*)out)[(size_t)node * 32 + cbase] = pk.u;
                s0 += v0; s1 += v1; s2 += v2; s3 += v3;
                q0 += v0 * v0; q1 += v1 * v1; q2 += v2 * v2; q3 += v3 * v3;
            }
        }
    }
    if (es == 0) {
        *(float4*)&ls[w][fl * 4] = make_float4(s0, s1, s2, s3);
        *(float4*)&lss[w][fl * 4] = make_float4(q0, q1, q2, q3);
    }
    __syncthreads();
    if (tid < 16) {
        float s = ls[0][tid] + ls[1][tid] + ls[2][tid] + ls[3][tid];
        float q = lss[0][tid] + lss[1][tid] + lss[2][tid] + lss[3][tid];
        int stripe = (gb & (NSTRIPE - 1)) * 128;
        atomicAdd(&S[stripe + g * 16 + tid], s);
        atomicAdd(&SS[stripe + g * 16 + tid], q);
    }
}

// ---------------- final: out = tanh(relu(bn(tf)) @ Wf2 + bf2), BN-finalize fused -------

__global__ __launch_bounds__(256) void k_final(const float* __restrict__ tf,
                                               const float* __restrict__ S, const float* __restrict__ SS,
                                               const float* __restrict__ gf, const float* __restrict__ btf,
                                               const float* __restrict__ Wf2, const float* __restrict__ bf2,
                                               float* __restrict__ out, int n) {
    __shared__ float Af[32], Cf[32];
    int tid = threadIdx.x;
    if (tid < 32) {
        float s = 0.f, q = 0.f;
#pragma unroll
        for (int k = 0; k < NSTRIPE; ++k) { s += S[k * 128 + tid]; q += SS[k * 128 + tid]; }
        float mu = s / (float)n;
        float var = q / (float)n - mu * mu;
        float inv = rsqrtf(var + EPS);
        Af[tid] = gf[tid] * inv;
        Cf[tid] = btf[tid] - mu * gf[tid] * inv;
    }
    __syncthreads();
    int node = blockIdx.x * 256 + tid;
    if (node >= n) return;
    float o0 = bf2[0], o1 = bf2[1];
    const float4* t4 = (const float4*)(tf + (size_t)node * 32);
#pragma unroll
    for (int q = 0; q < 8; ++q) {
        float4 v = t4[q];
        float vv[4] = {v.x, v.y, v.z, v.w};
#pragma unroll
        for (int r = 0; r < 4; ++r) {
            int j = q * 4 + r;
            float f = fmaxf(vv[r] * Af[j] + Cf[j], 0.f);
            o0 += f * Wf2[2 * j];
            o1 += f * Wf2[2 * j + 1];
        }
    }
    out[2 * node] = tanhf(o0);
    out[2 * node + 1] = tanhf(o1);
}

// ---------------- launch ----------------

extern "C" void kernel_launch(void* const* d_in, const int* in_sizes, int n_in,
                              void* d_out, int out_size, void* d_ws, size_t ws_size,
                              hipStream_t stream) {
    const float* x   = (const float*)d_in[0];
    const int*   ei  = (const int*)d_in[1];
    const float* We  = (const float*)d_in[2];
    const float* be  = (const float*)d_in[3];
    const float* W1  = (const float*)d_in[4];
    const float* b1  = (const float*)d_in[5];
    const float* g1  = (const float*)d_in[6];
    const float* bt1 = (const float*)d_in[7];
    const float* W2  = (const float*)d_in[8];
    const float* b2  = (const float*)d_in[9];
    const float* g2  = (const float*)d_in[10];
    const float* bt2 = (const float*)d_in[11];
    const float* W3  = (const float*)d_in[12];
    const float* b3  = (const float*)d_in[13];
    const float* g3  = (const float*)d_in[14];
    const float* bt3 = (const float*)d_in[15];
    const float* Wf1 = (const float*)d_in[16];
    const float* bf1 = (const float*)d_in[17];
    const float* gf  = (const float*)d_in[18];
    const float* btf = (const float*)d_in[19];
    const float* Wf2 = (const float*)d_in[20];
    const float* bf2 = (const float*)d_in[21];
    float* out = (float*)d_out;

    const int n = in_sizes[0] / 2;      // x is [N,2]
    const int e = in_sizes[1] / 2;      // edge_index is [2,E]
    const int* srcp = ei;
    const int* dstp = ei + e;
    const int nbk = (n + BK - 1) / BK;

    char* p = (char*)d_ws;
    auto alloc = [&](size_t bytes) { void* r = (void*)p; p += (bytes + 255) & ~(size_t)255; return r; };
    int*       bcount = (int*)alloc((size_t)nbk * 16 * 4);
    int*       boffs  = (int*)alloc((size_t)(nbk + 1) * 4);
    int*       bcur   = (int*)alloc((size_t)nbk * 16 * 4);
    int*       btmp   = (int*)alloc((size_t)e * 4);
    int*       csr    = (int*)alloc((size_t)e * 4);
    int*       offs   = (int*)alloc((size_t)(n + 1) * 4);
    float*     dinv   = (float*)alloc((size_t)n * 4);
    __half2*   h      = (__half2*)alloc((size_t)n * HID * 2);
    __half2*   th     = (__half2*)alloc((size_t)n * HID * 2);
    __half2*   agg    = (__half2*)alloc((size_t)n * HID * 2);
    float*     tf     = (float*)alloc((size_t)n * 32 * 4);
    float*     bnAll  = (float*)alloc(8 * NSTRIPE * 128 * 4);   // S0..S2,SH | SS0..SS2,SSH
    _Float16*  wt1    = (_Float16*)alloc(128 * 128 * 2);
    _Float16*  wt2    = (_Float16*)alloc(128 * 128 * 2);
    _Float16*  wt3    = (_Float16*)alloc(128 * 128 * 2);
    _Float16*  wtf    = (_Float16*)alloc(32 * 128 * 2);

    float* S0 = bnAll;             float* SS0 = bnAll + 4 * NSTRIPE * 128;
    float* S1 = S0 + NSTRIPE*128;  float* SS1 = SS0 + NSTRIPE*128;
    float* S2 = S1 + NSTRIPE*128;  float* SS2 = SS1 + NSTRIPE*128;
    float* SH = S2 + NSTRIPE*128;  float* SSH = SS2 + NSTRIPE*128;

    hipMemsetAsync(bcount, 0, (size_t)nbk * 16 * 4, stream);
    hipMemsetAsync(bnAll, 0, 8 * NSTRIPE * 128 * 4, stream);
    k_bhist<<<(e + 4095) / 4096, 256, 0, stream>>>(dstp, bcount, e, nbk);
    k_bscan<<<1, 1024, 0, stream>>>(bcount, boffs, bcur, nbk, e);
    k_bscatter<<<256, 1024, 0, stream>>>(srcp, dstp, bcur, btmp, e, nbk);
    k_bsort<<<nbk, 256, 0, stream>>>(btmp, boffs, csr, offs, dinv, n, e);
    k_prepw<<<64, 256, 0, stream>>>(W1, wt1);
    k_prepw<<<64, 256, 0, stream>>>(W2, wt2);
    k_prepw<<<64, 256, 0, stream>>>(W3, wt3);
    k_prepwf<<<16, 256, 0, stream>>>(Wf1, wtf);

    // layer 1 (embed fused into GEMM staging; h written fp16)
    k_mm1<<<(n + 63) / 64, 256, 0, stream>>>(x, We, be, wt1, dinv, th, h, n);
    k_agg<<<4096, 256, 0, stream>>>(th, offs, csr, dinv, b1, agg, S0, SS0, n);

    // layer 2 (BN1 finalize+apply+relu+residual fused into GEMM)
    k_mmf<<<(n + 63) / 64, 256, 0, stream>>>(agg, h, S0, SS0, g1, bt1, wt2, dinv, th, n);
    k_agg<<<4096, 256, 0, stream>>>(th, offs, csr, dinv, b2, agg, S1, SS1, n);

    // layer 3
    k_mmf<<<(n + 63) / 64, 256, 0, stream>>>(agg, h, S1, SS1, g2, bt2, wt3, dinv, th, n);
    k_agg<<<4096, 256, 0, stream>>>(th, offs, csr, dinv, b3, agg, S2, SS2, n);

    // head (BN3 finalize+apply+relu+residual + GEMM + head-BN stats)
    k_mmh<<<(n + 63) / 64, 256, 0, stream>>>(agg, h, S2, SS2, g3, bt3, wtf, bf1, tf, SH, SSH, n);

    // final (head-BN finalize fused)
    k_final<<<(n + 255) / 256, 256, 0, stream>>>(tf, SH, SSH, gf, btf, Wf2, bf2, out, n);
}

// Round 15
// 475.234 us; speedup vs baseline: 1.9948x; 1.9948x over previous
//
#include <hip/hip_runtime.h>
#include <hip/hip_fp16.h>
#include <math.h>

#define HID 128
#define EPS 1e-5f
#define BK 64          // dst nodes per bucket
#define MAXNBK 2048    // supports n <= 131072
#define NSTRIPE 16     // BN-stats atomic striping
#define PADK 136       // fp16 LDS row stride: 68 words % 32 = 4 -> conflict-free MFMA frag reads

typedef _Float16 half8 __attribute__((ext_vector_type(8)));
typedef float f32x4 __attribute__((ext_vector_type(4)));

// ---------------- bucketed graph preprocessing ----------------
// btmp entry: (src << 6) | (dst & 63)

__global__ __launch_bounds__(256) void k_bhist(const int* __restrict__ dst, int* __restrict__ bcount,
                                               int e, int nbk) {
    __shared__ int hist[MAXNBK];
    for (int i = threadIdx.x; i < nbk; i += 256) hist[i] = 0;
    __syncthreads();
    int base = blockIdx.x * 4096;
    int end = min(base + 4096, e);
    for (int i = base + threadIdx.x; i < end; i += 256) atomicAdd(&hist[dst[i] >> 6], 1);
    __syncthreads();
    for (int i = threadIdx.x; i < nbk; i += 256) {
        int c = hist[i];
        if (c) atomicAdd(&bcount[i * 16], c);
    }
}

__global__ __launch_bounds__(1024) void k_bscan(const int* __restrict__ bcount, int* __restrict__ boffs,
                                                int* __restrict__ bcur, int nbk, int e) {
    __shared__ int lds[1024];
    int tid = threadIdx.x;
    int i0 = 2 * tid, i1 = 2 * tid + 1;
    int a = (i0 < nbk) ? bcount[i0 * 16] : 0;
    int b = (i1 < nbk) ? bcount[i1 * 16] : 0;
    lds[tid] = a + b;
    __syncthreads();
    for (int off = 1; off < 1024; off <<= 1) {
        int v = (tid >= off) ? lds[tid - off] : 0;
        __syncthreads();
        lds[tid] += v;
        __syncthreads();
    }
    int excl = lds[tid] - (a + b);
    if (i0 < nbk) { boffs[i0] = excl;     bcur[i0 * 16] = excl; }
    if (i1 < nbk) { boffs[i1] = excl + a; bcur[i1 * 16] = excl + a; }
    if (tid == 1023) boffs[nbk] = e;
}

__global__ __launch_bounds__(1024) void k_bscatter(const int* __restrict__ src, const int* __restrict__ dst,
                                                   int* __restrict__ bcur, int* __restrict__ btmp,
                                                   int e, int nbk) {
    __shared__ int hist[MAXNBK];
    int tid = threadIdx.x;
    for (int i = tid; i < nbk; i += 1024) hist[i] = 0;
    __syncthreads();
    int per = (e + gridDim.x - 1) / gridDim.x;
    int base = blockIdx.x * per;
    int end = min(base + per, e);
    for (int i = base + tid; i < end; i += 1024) atomicAdd(&hist[dst[i] >> 6], 1);
    __syncthreads();
    for (int i = tid; i < nbk; i += 1024) {
        int c = hist[i];
        hist[i] = c ? atomicAdd(&bcur[i * 16], c) : 0;
    }
    __syncthreads();
    for (int i = base + tid; i < end; i += 1024) {
        int d = dst[i];
        int pos = atomicAdd(&hist[d >> 6], 1);          // LDS int atomic (native)
        btmp[pos] = (src[i] << 6) | (d & 63);
    }
}

__global__ __launch_bounds__(256) void k_bsort(const int* __restrict__ btmp, const int* __restrict__ boffs,
                                               int* __restrict__ csr, int* __restrict__ offs,
                                               float* __restrict__ dinv, int n, int etot) {
    __shared__ int cnt[BK];
    __shared__ int cur[BK];
    int b = blockIdx.x, tid = threadIdx.x;
    if (tid < BK) cnt[tid] = 0;
    __syncthreads();
    int e0 = boffs[b], e1 = boffs[b + 1];
    for (int i = e0 + tid; i < e1; i += 256) atomicAdd(&cnt[btmp[i] & 63], 1);
    __syncthreads();
    if (tid == 0) {
        int run = 0;
        for (int d = 0; d < BK; ++d) { cur[d] = run; run += cnt[d]; }
    }
    __syncthreads();
    if (tid < BK) {
        int node = b * BK + tid;
        if (node < n) {
            offs[node] = e0 + cur[tid];
            dinv[node] = rsqrtf((float)(cnt[tid] + 1));  // +1 self-loop
        }
    }
    if (b == 0 && tid == 0) offs[n] = etot;
    __syncthreads();
    for (int i = e0 + tid; i < e1; i += 256) {
        int p = btmp[i];
        int pos = e0 + atomicAdd(&cur[p & 63], 1);
        csr[pos] = p >> 6;
    }
}

// ---------------- weight transpose to fp16 ----------------

__global__ void k_prepw(const float* __restrict__ W, _Float16* __restrict__ Wt) {
    int idx = blockIdx.x * 256 + threadIdx.x;   // 128*128
    int k = idx >> 7, nn = idx & 127;
    Wt[nn * 128 + k] = (_Float16)W[k * 128 + nn];
}

__global__ void k_prepwf(const float* __restrict__ W, _Float16* __restrict__ Wt) {
    int idx = blockIdx.x * 256 + threadIdx.x;   // 128*32
    int k = idx >> 5, nn = idx & 31;
    Wt[nn * 128 + k] = (_Float16)W[k * 32 + nn];
}

// ---------------- MFMA GEMM layer 1 with fused embed -----------------------------------

__global__ __launch_bounds__(256) void k_mm1(const float* __restrict__ x, const float* __restrict__ We,
                                             const float* __restrict__ be, const _Float16* __restrict__ Wt,
                                             const float* __restrict__ dinv, __half2* __restrict__ th,
                                             __half2* __restrict__ h, int n) {
    __shared__ __attribute__((aligned(16))) _Float16 Ah[64][PADK];
    __shared__ __attribute__((aligned(16))) _Float16 Bh[128][PADK];
    __shared__ float W0s[128], W1s[128], bes[128];
    int tid = threadIdx.x;
    int nb = blockIdx.x * 64;
    if (tid < 128) { W0s[tid] = We[tid]; W1s[tid] = We[128 + tid]; bes[tid] = be[tid]; }
    __syncthreads();
    uint2* h2p = (uint2*)h;
    const float2* x2 = (const float2*)x;
#pragma unroll
    for (int r = 0; r < 8; ++r) {
        int idx = r * 256 + tid;
        int ni = idx >> 5, k4 = idx & 31;
        int node = nb + ni;
        float4 v = make_float4(0.f, 0.f, 0.f, 0.f);
        union { __half2 h2[2]; uint2 u; } pk;
        if (node < n) {
            float2 xx = x2[node];
            float4 w0 = *((const float4*)&W0s[k4 * 4]);
            float4 w1 = *((const float4*)&W1s[k4 * 4]);
            float4 bb = *((const float4*)&bes[k4 * 4]);
            v.x = fmaxf(xx.x * w0.x + xx.y * w1.x + bb.x, 0.f);
            v.y = fmaxf(xx.x * w0.y + xx.y * w1.y + bb.y, 0.f);
            v.z = fmaxf(xx.x * w0.z + xx.y * w1.z + bb.z, 0.f);
            v.w = fmaxf(xx.x * w0.w + xx.y * w1.w + bb.w, 0.f);
            pk.h2[0] = __floats2half2_rn(v.x, v.y);
            pk.h2[1] = __floats2half2_rn(v.z, v.w);
            h2p[(size_t)node * 32 + k4] = pk.u;   // h stored fp16 for layer-2 residual
        } else {
            pk.h2[0] = __floats2half2_rn(0.f, 0.f);
            pk.h2[1] = __floats2half2_rn(0.f, 0.f);
        }
        *(uint2*)&Ah[ni][k4 * 4] = pk.u;
    }
    const uint4* wt4 = (const uint4*)Wt;
#pragma unroll
    for (int r = 0; r < 8; ++r) {
        int idx = r * 256 + tid;
        int row = idx >> 4, ch = idx & 15;
        *(uint4*)&Bh[row][ch * 8] = wt4[row * 16 + ch];
    }
    __syncthreads();
    int lane = tid & 63, w = tid >> 6;
    int mrow = lane & 15, quad = lane >> 4;
    f32x4 acc[8];
#pragma unroll
    for (int t = 0; t < 8; ++t) acc[t] = (f32x4){0.f, 0.f, 0.f, 0.f};
#pragma unroll
    for (int kc = 0; kc < 4; ++kc) {
        half8 av = *(half8*)&Ah[w * 16 + mrow][kc * 32 + quad * 8];
#pragma unroll
        for (int t = 0; t < 8; ++t) {
            half8 bv = *(half8*)&Bh[t * 16 + mrow][kc * 32 + quad * 8];
            acc[t] = __builtin_amdgcn_mfma_f32_16x16x32_f16(av, bv, acc[t], 0, 0, 0);
        }
    }
    float dv[4];
#pragma unroll
    for (int r = 0; r < 4; ++r) {
        int node = nb + w * 16 + quad * 4 + r;
        dv[r] = (node < n) ? dinv[node] : 0.f;
    }
    __syncthreads();   // Ah reads done; reuse as output repack tile
#pragma unroll
    for (int t = 0; t < 8; ++t)
#pragma unroll
        for (int r = 0; r < 4; ++r)
            Ah[w * 16 + quad * 4 + r][t * 16 + mrow] = (_Float16)(acc[t][r] * dv[r]);
    __syncthreads();
#pragma unroll
    for (int it = 0; it < 4; ++it) {
        int idx = it * 256 + tid;
        int row = idx >> 4, ch = idx & 15;
        int node = nb + row;
        if (node < n)
            ((uint4*)th)[(size_t)node * 16 + ch] = *(uint4*)&Ah[row][ch * 8];
    }
}

// ---------------- MFMA GEMM fused with BN-finalize+apply+ReLU+residual (layers 2,3) ----

__global__ __launch_bounds__(256) void k_mmf(const __half2* __restrict__ agg, __half2* __restrict__ h,
                                             const float* __restrict__ S, const float* __restrict__ SS,
                                             const float* __restrict__ g, const float* __restrict__ bt,
                                             const _Float16* __restrict__ Wt, const float* __restrict__ dinv,
                                             __half2* __restrict__ th, int n) {
    __shared__ __attribute__((aligned(16))) _Float16 Ah[64][PADK];
    __shared__ __attribute__((aligned(16))) _Float16 Bh[128][PADK];
    __shared__ float As[128], Cs[128];
    int tid = threadIdx.x;
    int nb = blockIdx.x * 64;
    if (tid < 128) {
        float s = 0.f, q = 0.f;
#pragma unroll
        for (int k = 0; k < NSTRIPE; ++k) { s += S[k * 128 + tid]; q += SS[k * 128 + tid]; }
        float mu = s / (float)n;
        float var = q / (float)n - mu * mu;
        float inv = rsqrtf(var + EPS);
        As[tid] = g[tid] * inv;
        Cs[tid] = bt[tid] - mu * g[tid] * inv;
    }
    __syncthreads();
    const uint2* a2p = (const uint2*)agg;
    uint2* h2p = (uint2*)h;
#pragma unroll
    for (int r = 0; r < 8; ++r) {
        int idx = r * 256 + tid;
        int ni = idx >> 5, k4 = idx & 31;
        int node = nb + ni;
        union { __half2 h2[2]; uint2 u; } pk;
        if (node < n) {
            uint2 au = a2p[(size_t)node * 32 + k4];
            uint2 hu = h2p[(size_t)node * 32 + k4];
            float2 a01 = __half22float2(*(__half2*)&au.x);
            float2 a23 = __half22float2(*(__half2*)&au.y);
            float2 h01 = __half22float2(*(__half2*)&hu.x);
            float2 h23 = __half22float2(*(__half2*)&hu.y);
            float4 aa = *((const float4*)&As[k4 * 4]);
            float4 cc = *((const float4*)&Cs[k4 * 4]);
            float v0 = fmaxf(a01.x * aa.x + cc.x, 0.f) + h01.x;
            float v1 = fmaxf(a01.y * aa.y + cc.y, 0.f) + h01.y;
            float v2 = fmaxf(a23.x * aa.z + cc.z, 0.f) + h23.x;
            float v3 = fmaxf(a23.y * aa.w + cc.w, 0.f) + h23.y;
            pk.h2[0] = __floats2half2_rn(v0, v1);
            pk.h2[1] = __floats2half2_rn(v2, v3);
            h2p[(size_t)node * 32 + k4] = pk.u;   // in-place: element owned by one thread
        } else {
            pk.h2[0] = __floats2half2_rn(0.f, 0.f);
            pk.h2[1] = __floats2half2_rn(0.f, 0.f);
        }
        *(uint2*)&Ah[ni][k4 * 4] = pk.u;
    }
    const uint4* wt4 = (const uint4*)Wt;
#pragma unroll
    for (int r = 0; r < 8; ++r) {
        int idx = r * 256 + tid;
        int row = idx >> 4, ch = idx & 15;
        *(uint4*)&Bh[row][ch * 8] = wt4[row * 16 + ch];
    }
    __syncthreads();
    int lane = tid & 63, w = tid >> 6;
    int mrow = lane & 15, quad = lane >> 4;
    f32x4 acc[8];
#pragma unroll
    for (int t = 0; t < 8; ++t) acc[t] = (f32x4){0.f, 0.f, 0.f, 0.f};
#pragma unroll
    for (int kc = 0; kc < 4; ++kc) {
        half8 av = *(half8*)&Ah[w * 16 + mrow][kc * 32 + quad * 8];
#pragma unroll
        for (int t = 0; t < 8; ++t) {
            half8 bv = *(half8*)&Bh[t * 16 + mrow][kc * 32 + quad * 8];
            acc[t] = __builtin_amdgcn_mfma_f32_16x16x32_f16(av, bv, acc[t], 0, 0, 0);
        }
    }
    float dv[4];
#pragma unroll
    for (int r = 0; r < 4; ++r) {
        int node = nb + w * 16 + quad * 4 + r;
        dv[r] = (node < n) ? dinv[node] : 0.f;
    }
    __syncthreads();
#pragma unroll
    for (int t = 0; t < 8; ++t)
#pragma unroll
        for (int r = 0; r < 4; ++r)
            Ah[w * 16 + quad * 4 + r][t * 16 + mrow] = (_Float16)(acc[t][r] * dv[r]);
    __syncthreads();
#pragma unroll
    for (int it = 0; it < 4; ++it) {
        int idx = it * 256 + tid;
        int row = idx >> 4, ch = idx & 15;
        int node = nb + row;
        if (node < n)
            ((uint4*)th)[(size_t)node * 16 + ch] = *(uint4*)&Ah[row][ch * 8];
    }
}

// ---------------- MFMA head GEMM: BN-finalize+apply+ReLU+residual -> @Wf1+bf1 + stats --

__global__ __launch_bounds__(256) void k_mmh(const __half2* __restrict__ agg, const __half2* __restrict__ h,
                                             const float* __restrict__ Sin, const float* __restrict__ SSin,
                                             const float* __restrict__ g, const float* __restrict__ bt,
                                             const _Float16* __restrict__ Wt, const float* __restrict__ bias,
                                             float* __restrict__ tf,
                                             float* __restrict__ S, float* __restrict__ SS, int n) {
    __shared__ __attribute__((aligned(16))) _Float16 Ah[64][PADK];
    __shared__ __attribute__((aligned(16))) _Float16 Bh[32][PADK];
    __shared__ float Ds[64][36];
    __shared__ float As[128], Cs[128];
    __shared__ float sredS[4][8][4], sredQ[4][8][4];
    int tid = threadIdx.x;
    int nb = blockIdx.x * 64;
    if (tid < 128) {
        float s = 0.f, q = 0.f;
#pragma unroll
        for (int k = 0; k < NSTRIPE; ++k) { s += Sin[k * 128 + tid]; q += SSin[k * 128 + tid]; }
        float mu = s / (float)n;
        float var = q / (float)n - mu * mu;
        float inv = rsqrtf(var + EPS);
        As[tid] = g[tid] * inv;
        Cs[tid] = bt[tid] - mu * g[tid] * inv;
    }
    __syncthreads();
    const uint2* a2p = (const uint2*)agg;
    const uint2* h2p = (const uint2*)h;
#pragma unroll
    for (int r = 0; r < 8; ++r) {
        int idx = r * 256 + tid;
        int ni = idx >> 5, k4 = idx & 31;
        int node = nb + ni;
        union { __half2 h2[2]; uint2 u; } pk;
        if (node < n) {
            uint2 au = a2p[(size_t)node * 32 + k4];
            uint2 hu = h2p[(size_t)node * 32 + k4];
            float2 a01 = __half22float2(*(__half2*)&au.x);
            float2 a23 = __half22float2(*(__half2*)&au.y);
            float2 h01 = __half22float2(*(__half2*)&hu.x);
            float2 h23 = __half22float2(*(__half2*)&hu.y);
            float4 aa = *((const float4*)&As[k4 * 4]);
            float4 cc = *((const float4*)&Cs[k4 * 4]);
            float v0 = fmaxf(a01.x * aa.x + cc.x, 0.f) + h01.x;
            float v1 = fmaxf(a01.y * aa.y + cc.y, 0.f) + h01.y;
            float v2 = fmaxf(a23.x * aa.z + cc.z, 0.f) + h23.x;
            float v3 = fmaxf(a23.y * aa.w + cc.w, 0.f) + h23.y;
            pk.h2[0] = __floats2half2_rn(v0, v1);
            pk.h2[1] = __floats2half2_rn(v2, v3);
        } else {
            pk.h2[0] = __floats2half2_rn(0.f, 0.f);
            pk.h2[1] = __floats2half2_rn(0.f, 0.f);
        }
        *(uint2*)&Ah[ni][k4 * 4] = pk.u;
    }
    const uint4* wt4 = (const uint4*)Wt;
#pragma unroll
    for (int r = 0; r < 2; ++r) {
        int idx = r * 256 + tid;
        int row = idx >> 4, ch = idx & 15;
        *(uint4*)&Bh[row][ch * 8] = wt4[row * 16 + ch];
    }
    __syncthreads();
    int lane = tid & 63, w = tid >> 6;
    int mrow = lane & 15, quad = lane >> 4;
    f32x4 acc[2];
    acc[0] = (f32x4){0.f, 0.f, 0.f, 0.f};
    acc[1] = (f32x4){0.f, 0.f, 0.f, 0.f};
#pragma unroll
    for (int kc = 0; kc < 4; ++kc) {
        half8 av = *(half8*)&Ah[w * 16 + mrow][kc * 32 + quad * 8];
#pragma unroll
        for (int t = 0; t < 2; ++t) {
            half8 bv = *(half8*)&Bh[t * 16 + mrow][kc * 32 + quad * 8];
            acc[t] = __builtin_amdgcn_mfma_f32_16x16x32_f16(av, bv, acc[t], 0, 0, 0);
        }
    }
#pragma unroll
    for (int t = 0; t < 2; ++t)
#pragma unroll
        for (int r = 0; r < 4; ++r)
            Ds[w * 16 + quad * 4 + r][t * 16 + mrow] = acc[t][r];
    __syncthreads();
    float ps0 = 0.f, ps1 = 0.f, ps2 = 0.f, ps3 = 0.f;
    float pq0 = 0.f, pq1 = 0.f, pq2 = 0.f, pq3 = 0.f;
    int c4 = tid & 7;
    float4 bb = ((const float4*)bias)[c4];
#pragma unroll
    for (int it = 0; it < 2; ++it) {
        int idx = it * 256 + tid;
        int row = idx >> 3;
        int node = nb + row;
        if (node < n) {
            float v0 = Ds[row][c4 * 4 + 0] + bb.x;
            float v1 = Ds[row][c4 * 4 + 1] + bb.y;
            float v2 = Ds[row][c4 * 4 + 2] + bb.z;
            float v3 = Ds[row][c4 * 4 + 3] + bb.w;
            *((float4*)&tf[(size_t)node * 32 + c4 * 4]) = make_float4(v0, v1, v2, v3);
            ps0 += v0; ps1 += v1; ps2 += v2; ps3 += v3;
            pq0 += v0 * v0; pq1 += v1 * v1; pq2 += v2 * v2; pq3 += v3 * v3;
        }
    }
#pragma unroll
    for (int off = 8; off < 64; off <<= 1) {
        ps0 += __shfl_down(ps0, off); ps1 += __shfl_down(ps1, off);
        ps2 += __shfl_down(ps2, off); ps3 += __shfl_down(ps3, off);
        pq0 += __shfl_down(pq0, off); pq1 += __shfl_down(pq1, off);
        pq2 += __shfl_down(pq2, off); pq3 += __shfl_down(pq3, off);
    }
    if (lane < 8) {
        sredS[w][lane][0] = ps0; sredS[w][lane][1] = ps1; sredS[w][lane][2] = ps2; sredS[w][lane][3] = ps3;
        sredQ[w][lane][0] = pq0; sredQ[w][lane][1] = pq1; sredQ[w][lane][2] = pq2; sredQ[w][lane][3] = pq3;
    }
    __syncthreads();
    if (tid < 32) {
        int cc4 = tid >> 2, j = tid & 3;
        float s = sredS[0][cc4][j] + sredS[1][cc4][j] + sredS[2][cc4][j] + sredS[3][cc4][j];
        float q = sredQ[0][cc4][j] + sredQ[1][cc4][j] + sredQ[2][cc4][j] + sredQ[3][cc4][j];
        int stripe = (blockIdx.x & (NSTRIPE - 1)) * 128;
        atomicAdd(&S[stripe + tid], s);
        atomicAdd(&SS[stripe + tid], q);
    }
}

// ---------------- aggregation + fused BN stats (R10/R13 dual-edge — proven best) -------
// Lane l loads 8 B (4 feats) of edge (e + (l>>5)): 2 edge rows per wave-instr, VGPR 32,
// occupancy ~74%, full cache-line utilization (R14's 32B-slice variant tripled FETCH).

__global__ __launch_bounds__(256) void k_agg(const __half2* __restrict__ t, const int* __restrict__ offs,
                                             const int* __restrict__ csr, const float* __restrict__ dinv,
                                             const float* __restrict__ bias, __half2* __restrict__ out,
                                             float* __restrict__ S, float* __restrict__ SS, int n) {
    __shared__ float ls[4][128];
    __shared__ float lss[4][128];
    int tid = threadIdx.x;
    int lane = tid & 63, w = tid >> 6;
    int sub = lane >> 5, fl = lane & 31;
    const uint2* t4 = (const uint2*)t;
    float4 bb = ((const float4*)bias)[fl];
    float s0 = 0.f, s1 = 0.f, s2 = 0.f, s3 = 0.f;
    float q0 = 0.f, q1 = 0.f, q2 = 0.f, q3 = 0.f;
    float selfm = (sub == 0) ? 1.f : 0.f;
    int ngrp = (n + 3) >> 2;
    for (int grp = blockIdx.x; grp < ngrp; grp += gridDim.x) {
        int node = grp * 4 + w;
        if (node < n) {
            uint2 rv = t4[(size_t)node * 32 + fl];
            float2 f0 = __half22float2(*(__half2*)&rv.x);
            float2 f1 = __half22float2(*(__half2*)&rv.y);
            float a0 = f0.x * selfm, a1 = f0.y * selfm, a2 = f1.x * selfm, a3 = f1.y * selfm;
            int e0 = offs[node], e1 = offs[node + 1];
            for (int e = e0; e < e1; e += 8) {
                int i0 = e + sub, i1 = e + 2 + sub, i2 = e + 4 + sub, i3 = e + 6 + sub;
                int c0 = csr[min(i0, e1 - 1)];
                int c1 = csr[min(i1, e1 - 1)];
                int c2 = csr[min(i2, e1 - 1)];
                int c3 = csr[min(i3, e1 - 1)];
                uint2 r0 = t4[(size_t)c0 * 32 + fl];
                uint2 r1 = t4[(size_t)c1 * 32 + fl];
                uint2 r2 = t4[(size_t)c2 * 32 + fl];
                uint2 r3 = t4[(size_t)c3 * 32 + fl];
                float m0 = (i0 < e1) ? 1.f : 0.f;
                float m1 = (i1 < e1) ? 1.f : 0.f;
                float m2 = (i2 < e1) ? 1.f : 0.f;
                float m3 = (i3 < e1) ? 1.f : 0.f;
                float2 g0 = __half22float2(*(__half2*)&r0.x), g1 = __half22float2(*(__half2*)&r0.y);
                a0 += m0 * g0.x; a1 += m0 * g0.y; a2 += m0 * g1.x; a3 += m0 * g1.y;
                g0 = __half22float2(*(__half2*)&r1.x); g1 = __half22float2(*(__half2*)&r1.y);
                a0 += m1 * g0.x; a1 += m1 * g0.y; a2 += m1 * g1.x; a3 += m1 * g1.y;
                g0 = __half22float2(*(__half2*)&r2.x); g1 = __half22float2(*(__half2*)&r2.y);
                a0 += m2 * g0.x; a1 += m2 * g0.y; a2 += m2 * g1.x; a3 += m2 * g1.y;
                g0 = __half22float2(*(__half2*)&r3.x); g1 = __half22float2(*(__half2*)&r3.y);
                a0 += m3 * g0.x; a1 += m3 * g0.y; a2 += m3 * g1.x; a3 += m3 * g1.y;
            }
            a0 += __shfl_down(a0, 32);
            a1 += __shfl_down(a1, 32);
            a2 += __shfl_down(a2, 32);
            a3 += __shfl_down(a3, 32);
            if (sub == 0) {
                float di = dinv[node];
                float v0 = a0 * di + bb.x, v1 = a1 * di + bb.y;
                float v2 = a2 * di + bb.z, v3 = a3 * di + bb.w;
                union { __half2 h2[2]; uint2 u; } pk;
                pk.h2[0] = __floats2half2_rn(v0, v1);
                pk.h2[1] = __floats2half2_rn(v2, v3);
                ((uint2*)out)[(size_t)node * 32 + fl] = pk.u;
                s0 += v0; s1 += v1; s2 += v2; s3 += v3;
                q0 += v0 * v0; q1 += v1 * v1; q2 += v2 * v2; q3 += v3 * v3;
            }
        }
    }
    if (sub == 0) {
        ((float4*)&ls[w][0])[fl] = make_float4(s0, s1, s2, s3);
        ((float4*)&lss[w][0])[fl] = make_float4(q0, q1, q2, q3);
    }
    __syncthreads();
    if (tid < 128) {
        float s = ls[0][tid] + ls[1][tid] + ls[2][tid] + ls[3][tid];
        float q = lss[0][tid] + lss[1][tid] + lss[2][tid] + lss[3][tid];
        int stripe = (blockIdx.x & (NSTRIPE - 1)) * 128;
        atomicAdd(&S[stripe + tid], s);
        atomicAdd(&SS[stripe + tid], q);
    }
}

// ---------------- final: out = tanh(relu(bn(tf)) @ Wf2 + bf2), BN-finalize fused -------

__global__ __launch_bounds__(256) void k_final(const float* __restrict__ tf,
                                               const float* __restrict__ S, const float* __restrict__ SS,
                                               const float* __restrict__ gf, const float* __restrict__ btf,
                                               const float* __restrict__ Wf2, const float* __restrict__ bf2,
                                               float* __restrict__ out, int n) {
    __shared__ float Af[32], Cf[32];
    int tid = threadIdx.x;
    if (tid < 32) {
        float s = 0.f, q = 0.f;
#pragma unroll
        for (int k = 0; k < NSTRIPE; ++k) { s += S[k * 128 + tid]; q += SS[k * 128 + tid]; }
        float mu = s / (float)n;
        float var = q / (float)n - mu * mu;
        float inv = rsqrtf(var + EPS);
        Af[tid] = gf[tid] * inv;
        Cf[tid] = btf[tid] - mu * gf[tid] * inv;
    }
    __syncthreads();
    int node = blockIdx.x * 256 + tid;
    if (node >= n) return;
    float o0 = bf2[0], o1 = bf2[1];
    const float4* t4 = (const float4*)(tf + (size_t)node * 32);
#pragma unroll
    for (int q = 0; q < 8; ++q) {
        float4 v = t4[q];
        float vv[4] = {v.x, v.y, v.z, v.w};
#pragma unroll
        for (int r = 0; r < 4; ++r) {
            int j = q * 4 + r;
            float f = fmaxf(vv[r] * Af[j] + Cf[j], 0.f);
            o0 += f * Wf2[2 * j];
            o1 += f * Wf2[2 * j + 1];
        }
    }
    out[2 * node] = tanhf(o0);
    out[2 * node + 1] = tanhf(o1);
}

// ---------------- launch ----------------

extern "C" void kernel_launch(void* const* d_in, const int* in_sizes, int n_in,
                              void* d_out, int out_size, void* d_ws, size_t ws_size,
                              hipStream_t stream) {
    const float* x   = (const float*)d_in[0];
    const int*   ei  = (const int*)d_in[1];
    const float* We  = (const float*)d_in[2];
    const float* be  = (const float*)d_in[3];
    const float* W1  = (const float*)d_in[4];
    const float* b1  = (const float*)d_in[5];
    const float* g1  = (const float*)d_in[6];
    const float* bt1 = (const float*)d_in[7];
    const float* W2  = (const float*)d_in[8];
    const float* b2  = (const float*)d_in[9];
    const float* g2  = (const float*)d_in[10];
    const float* bt2 = (const float*)d_in[11];
    const float* W3  = (const float*)d_in[12];
    const float* b3  = (const float*)d_in[13];
    const float* g3  = (const float*)d_in[14];
    const float* bt3 = (const float*)d_in[15];
    const float* Wf1 = (const float*)d_in[16];
    const float* bf1 = (const float*)d_in[17];
    const float* gf  = (const float*)d_in[18];
    const float* btf = (const float*)d_in[19];
    const float* Wf2 = (const float*)d_in[20];
    const float* bf2 = (const float*)d_in[21];
    float* out = (float*)d_out;

    const int n = in_sizes[0] / 2;      // x is [N,2]
    const int e = in_sizes[1] / 2;      // edge_index is [2,E]
    const int* srcp = ei;
    const int* dstp = ei + e;
    const int nbk = (n + BK - 1) / BK;

    char* p = (char*)d_ws;
    auto alloc = [&](size_t bytes) { void* r = (void*)p; p += (bytes + 255) & ~(size_t)255; return r; };
    int*       bcount = (int*)alloc((size_t)nbk * 16 * 4);
    int*       boffs  = (int*)alloc((size_t)(nbk + 1) * 4);
    int*       bcur   = (int*)alloc((size_t)nbk * 16 * 4);
    int*       btmp   = (int*)alloc((size_t)e * 4);
    int*       csr    = (int*)alloc((size_t)e * 4);
    int*       offs   = (int*)alloc((size_t)(n + 1) * 4);
    float*     dinv   = (float*)alloc((size_t)n * 4);
    __half2*   h      = (__half2*)alloc((size_t)n * HID * 2);
    __half2*   th     = (__half2*)alloc((size_t)n * HID * 2);
    __half2*   agg    = (__half2*)alloc((size_t)n * HID * 2);
    float*     tf     = (float*)alloc((size_t)n * 32 * 4);
    float*     bnAll  = (float*)alloc(8 * NSTRIPE * 128 * 4);   // S0..S2,SH | SS0..SS2,SSH
    _Float16*  wt1    = (_Float16*)alloc(128 * 128 * 2);
    _Float16*  wt2    = (_Float16*)alloc(128 * 128 * 2);
    _Float16*  wt3    = (_Float16*)alloc(128 * 128 * 2);
    _Float16*  wtf    = (_Float16*)alloc(32 * 128 * 2);

    float* S0 = bnAll;             float* SS0 = bnAll + 4 * NSTRIPE * 128;
    float* S1 = S0 + NSTRIPE*128;  float* SS1 = SS0 + NSTRIPE*128;
    float* S2 = S1 + NSTRIPE*128;  float* SS2 = SS1 + NSTRIPE*128;
    float* SH = S2 + NSTRIPE*128;  float* SSH = SS2 + NSTRIPE*128;

    hipMemsetAsync(bcount, 0, (size_t)nbk * 16 * 4, stream);
    hipMemsetAsync(bnAll, 0, 8 * NSTRIPE * 128 * 4, stream);
    k_bhist<<<(e + 4095) / 4096, 256, 0, stream>>>(dstp, bcount, e, nbk);
    k_bscan<<<1, 1024, 0, stream>>>(bcount, boffs, bcur, nbk, e);
    k_bscatter<<<256, 1024, 0, stream>>>(srcp, dstp, bcur, btmp, e, nbk);
    k_bsort<<<nbk, 256, 0, stream>>>(btmp, boffs, csr, offs, dinv, n, e);
    k_prepw<<<64, 256, 0, stream>>>(W1, wt1);
    k_prepw<<<64, 256, 0, stream>>>(W2, wt2);
    k_prepw<<<64, 256, 0, stream>>>(W3, wt3);
    k_prepwf<<<16, 256, 0, stream>>>(Wf1, wtf);

    // layer 1 (embed fused into GEMM staging; h written fp16)
    k_mm1<<<(n + 63) / 64, 256, 0, stream>>>(x, We, be, wt1, dinv, th, h, n);
    k_agg<<<4096, 256, 0, stream>>>(th, offs, csr, dinv, b1, agg, S0, SS0, n);

    // layer 2 (BN1 finalize+apply+relu+residual fused into GEMM)
    k_mmf<<<(n + 63) / 64, 256, 0, stream>>>(agg, h, S0, SS0, g1, bt1, wt2, dinv, th, n);
    k_agg<<<4096, 256, 0, stream>>>(th, offs, csr, dinv, b2, agg, S1, SS1, n);

    // layer 3
    k_mmf<<<(n + 63) / 64, 256, 0, stream>>>(agg, h, S1, SS1, g2, bt2, wt3, dinv, th, n);
    k_agg<<<4096, 256, 0, stream>>>(th, offs, csr, dinv, b3, agg, S2, SS2, n);

    // head (BN3 finalize+apply+relu+residual + GEMM + head-BN stats)
    k_mmh<<<(n + 63) / 64, 256, 0, stream>>>(agg, h, S2, SS2, g3, bt3, wtf, bf1, tf, SH, SSH, n);

    // final (head-BN finalize fused)
    k_final<<<(n + 255) / 256, 256, 0, stream>>>(tf, SH, SSH, gf, btf, Wf2, bf2, out, n);
}